// Round 13
// baseline (242.538 us; speedup 1.0000x reference)
//
#include <hip/hip_runtime.h>
#include <stdint.h>

typedef int i32x4 __attribute__((ext_vector_type(4)));
typedef int i32x16 __attribute__((ext_vector_type(16)));

#define K_DIM 1024
#define BM 256
#define BN 256
#define NKT 16         // K-tiles of 64
#define NJOB 3         // persistent jobs per block

// 32-row fragment-ordered int8 layout (producers <-> GEMM):
// fragment (F = row/32, T = k/32) is 1KB at offset (F*32 + T)*1024; byte
// (l = b>>4, j = b&15) holds value[row = F*32 + (l&31)][k = T*32 + (l>>5)*16 + j].
// Matches mfma_i32_32x32x32_i8 A/B lane mapping. Every fragment = ONE coalesced
// 1KB load (gld_lds for A, b128-to-reg for B).

__device__ __forceinline__ int quant1(float v, float inv) {
  float t = rintf(v * inv);                 // round half-to-even, matches jnp.round
  t = fminf(fmaxf(t, -128.0f), 127.0f);     // clip(-n-1, n)
  return (int)t;
}

__device__ __forceinline__ void gld_lds16(const signed char* g, signed char* l) {
  typedef const __attribute__((address_space(1))) unsigned int* gp_t;
  typedef __attribute__((address_space(3))) unsigned int* lp_t;
  __builtin_amdgcn_global_load_lds((gp_t)(const void*)g, (lp_t)(void*)l, 16, 0, 0);
}

#define SB __builtin_amdgcn_sched_barrier(0)
#define BAR __builtin_amdgcn_s_barrier()

// ---------------- 1a) absmax partials ----------------
__global__ void absmax_part(const float* __restrict__ x, float* __restrict__ parts,
                            long long n4) {
  long long i = (long long)blockIdx.x * blockDim.x + threadIdx.x;
  const long long stride = (long long)gridDim.x * blockDim.x;
  const float4* x4 = (const float4*)x;
  float m = 0.0f;
  for (; i < n4; i += stride) {
    float4 v = x4[i];
    m = fmaxf(m, fmaxf(fmaxf(fabsf(v.x), fabsf(v.y)), fmaxf(fabsf(v.z), fabsf(v.w))));
  }
#pragma unroll
  for (int off = 32; off > 0; off >>= 1) m = fmaxf(m, __shfl_down(m, off, 64));
  __shared__ float sm[4];
  const int lane = threadIdx.x & 63, wid = threadIdx.x >> 6;
  if (lane == 0) sm[wid] = m;
  __syncthreads();
  if (threadIdx.x == 0)
    parts[blockIdx.x] = fmaxf(fmaxf(sm[0], sm[1]), fmaxf(sm[2], sm[3]));
}

// ---------------- 1b) absmax final reduce ----------------
__global__ void absmax_fin(const float* __restrict__ parts, unsigned int* __restrict__ amax_u,
                           int nparts) {
  const int t = threadIdx.x;
  float m = 0.0f;
  for (int i = t; i < nparts; i += 256) m = fmaxf(m, parts[i]);
#pragma unroll
  for (int off = 32; off > 0; off >>= 1) m = fmaxf(m, __shfl_down(m, off, 64));
  __shared__ float sm[4];
  const int lane = t & 63, wid = t >> 6;
  if (lane == 0) sm[wid] = m;
  __syncthreads();
  if (t == 0)
    amax_u[0] = __float_as_uint(fmaxf(fmaxf(sm[0], sm[1]), fmaxf(sm[2], sm[3])));
}

// ---------------- 2) weight quant + bias (32-frag wq) ----------------
__global__ void wquant_kernel(const float* __restrict__ w, const float* __restrict__ bias,
                              const unsigned int* __restrict__ amax_u,
                              signed char* __restrict__ wq,
                              float* __restrict__ bscale, float* __restrict__ bint) {
  const int o = blockIdx.x;
  const int t = threadIdx.x;          // k = 4t .. 4t+3
  float4 v = ((const float4*)(w + (size_t)o * K_DIM))[t];
  float m = fmaxf(fmaxf(fabsf(v.x), fabsf(v.y)), fmaxf(fabsf(v.z), fabsf(v.w)));
#pragma unroll
  for (int off = 32; off > 0; off >>= 1) m = fmaxf(m, __shfl_down(m, off, 64));
  __shared__ float sm[4];
  __shared__ float s_scale;
  const int lane = t & 63, wid = t >> 6;
  if (lane == 0) sm[wid] = m;
  __syncthreads();
  if (t == 0) {
    float wm = fmaxf(fmaxf(sm[0], sm[1]), fmaxf(sm[2], sm[3]));
    float wsc = fmaxf(wm, 1e-8f) / 127.0f;
    float asc = fmaxf(__uint_as_float(*amax_u), 1e-8f) / 127.0f;
    float bsc = wsc * asc;
    bscale[o] = bsc;
    bint[o] = rintf(bias[o] / bsc);
    s_scale = wsc;
  }
  __syncthreads();
  const float inv = 1.0f / s_scale;
  int q0 = quant1(v.x, inv), q1 = quant1(v.y, inv), q2 = quant1(v.z, inv), q3 = quant1(v.w, inv);
  unsigned int p = (unsigned)(q0 & 255) | ((unsigned)(q1 & 255) << 8) |
                   ((unsigned)(q2 & 255) << 16) | ((unsigned)(q3 & 255) << 24);
  const int F = o >> 5, T = t >> 3;
  const int l = (o & 31) | (((t >> 2) & 1) << 5);
  const int j = (t << 2) & 15;
  *(unsigned int*)(wq + (((size_t)(F * 32 + T)) << 10) + (l << 4) + j) = p;
}

// ---------------- 3) activation quant (coalesced -> LDS image -> 256B runs) ----------------
__global__ __launch_bounds__(256) void aquant_kernel(
    const float* __restrict__ x, const unsigned int* __restrict__ amax_u,
    uint4* __restrict__ q16) {
  __shared__ unsigned int limg[4096];   // 16KB
  const float asc = fmaxf(__uint_as_float(*amax_u), 1e-8f) / 127.0f;
  const float inv = 1.0f / asc;
  const int b = blockIdx.x;
  const int F32 = b >> 1, bh = b & 1;
  const int t = threadIdx.x;
  const int r = t >> 4, kq = t & 15;
  const float* rowp = x + (((size_t)b * 16 + r) << 10);
#pragma unroll
  for (int rep = 0; rep < 16; ++rep) {
    const int fi = rep * 16 + kq;
    float4 v = ((const float4*)rowp)[fi];
    int q0 = quant1(v.x, inv), q1 = quant1(v.y, inv), q2 = quant1(v.z, inv), q3 = quant1(v.w, inv);
    unsigned int p = (unsigned)(q0 & 255) | ((unsigned)(q1 & 255) << 8) |
                     ((unsigned)(q2 & 255) << 16) | ((unsigned)(q3 & 255) << 24);
    const int k0 = fi << 2;
    const int T32 = k0 >> 5;
    const int hi = (k0 >> 4) & 1;
    const int j = k0 & 15;
    limg[(((T32 << 1) | hi) << 6) + (r << 2) + (j >> 2)] = p;
  }
  __syncthreads();
  const uint4* src = (const uint4*)limg;
#pragma unroll
  for (int rep2 = 0; rep2 < 4; ++rep2) {
    const int e = rep2 * 256 + t;
    const int T32 = e >> 5, hs = (e >> 4) & 1, rr = e & 15;
    q16[(((size_t)(F32 * 32 + T32)) << 6) + (hs * 32 + bh * 16 + rr)] = src[e];
  }
}

// ---------------- 4) int8 GEMM: persistent 3-job blocks, continuous pipeline ----------------
// 256 blocks (1/CU), 512 thr = 8 waves (2x4). Per block: 3 jobs (same bn, bm+=8/job).
// K-pipeline NEVER drains across jobs: tiles 13-15 prefetch next job's tiles 0-2
// (buffer ring continues, vmcnt(8) invariant unchanged). Direct-store epilogue
// (no LDS/barrier) drains under the next job's K-loop.
__global__ __launch_bounds__(512, 2) void gemm_kernel(
    const signed char* __restrict__ A, const signed char* __restrict__ W,
    const float* __restrict__ bscale, const float* __restrict__ bint,
    float* __restrict__ out, int M, int N, int K) {
  extern __shared__ __align__(16) signed char smem[];   // 65536: 4 bufs x 16 frags x 1KB
  signed char* Abase = smem;

  // bijective job swizzle: q = j*256 + b -> wgid = (q&7)*96 + (q>>3)
  // -> bn = (b>>3)&3 fixed per block; bm = (b&7)*24 + ((b>>3)>>2) + 8j
  const int orig = blockIdx.x;
  const int wg = (orig & 7) * 96 + (orig >> 3);
  const int bn = wg & 3;
  const int bm0 = wg >> 2;
  const int m0 = bm0 * BM, n0 = bn * BN;

  const int tid = threadIdx.x;
  const int lane = tid & 63;
  const int wid = tid >> 6;          // 8 waves
  const int wr = wid >> 2;           // 2 wave-rows (128 rows)
  const int wc = wid & 3;            // 4 wave-cols (64 cols)

  // A: wave stages frags f=wid, wid+8 of each K-tile; job j adds j*2MB (64 F32 groups)
  const signed char* gaf =
      A + (((size_t)((m0 >> 5) + (wid >> 1)) * 32 + (wid & 1)) << 10) + (lane << 4);
  const size_t fs8 = (size_t)128 << 10;   // +8 frags = +4 F32 groups
  // B: wave's 2 col-groups; identical for all jobs
  const signed char* gbf =
      W + (((size_t)((n0 >> 5) + wc * 2) * 32) << 10) + (lane << 4);

  i32x16 acc[4][2];
#pragma unroll
  for (int i = 0; i < 4; i++)
#pragma unroll
    for (int j = 0; j < 2; j++)
#pragma unroll
      for (int r = 0; r < 16; r++) acc[i][j][r] = 0;

  i32x4 af[4][2];
  i32x4 bA[2][2], bB[2][2];

#define LOADB(L, tt)                                                           \
  do {                                                                         \
    L[0][0] = *(const i32x4*)(gbf + (((size_t)(tt) * 2 + 0) << 10));           \
    L[0][1] = *(const i32x4*)(gbf + (((size_t)(tt) * 2 + 1) << 10));           \
    L[1][0] = *(const i32x4*)(gbf + ((size_t)1 << 15) + (((size_t)(tt) * 2 + 0) << 10)); \
    L[1][1] = *(const i32x4*)(gbf + ((size_t)1 << 15) + (((size_t)(tt) * 2 + 1) << 10)); \
  } while (0)

#define ISSUEA_J(jj, tl)                                                       \
  do {                                                                         \
    const size_t jo_ = (size_t)(jj) << 21;  /* 2MB per job */                  \
    gld_lds16(gaf + jo_ + ((size_t)(tl) << 11),                                \
              Abase + ((((tl) & 3) * 16 + wid) << 10));                        \
    gld_lds16(gaf + jo_ + fs8 + ((size_t)(tl) << 11),                          \
              Abase + ((((tl) & 3) * 16 + wid + 8) << 10));                    \
  } while (0)

#define RD_A(t)                                                                \
  do {                                                                         \
    _Pragma("unroll") for (int m_ = 0; m_ < 4; m_++)                           \
      _Pragma("unroll") for (int k_ = 0; k_ < 2; k_++)                         \
        af[m_][k_] = *(const i32x4*)(Abase + ((((t) & 3) * 16 +                \
                        (wr * 4 + m_) * 2 + k_) << 10) + (lane << 4));         \
  } while (0)

#define MFMA16(U)                                                              \
  do {                                                                         \
    __builtin_amdgcn_s_setprio(1);                                             \
    _Pragma("unroll") for (int m_ = 0; m_ < 4; m_++)                           \
      _Pragma("unroll") for (int g_ = 0; g_ < 2; g_++)                         \
        _Pragma("unroll") for (int k_ = 0; k_ < 2; k_++)                       \
          acc[m_][g_] = __builtin_amdgcn_mfma_i32_32x32x32_i8(                 \
              af[m_][k_], U[g_][k_], acc[m_][g_], 0, 0, 0);                    \
    __builtin_amdgcn_s_setprio(0);                                             \
  } while (0)

// full-rate tile: always prefetch B((lt+1)&15) and A(job jj, tile tl), vmcnt(8)
#define TILEF(lt, U, L, JJ, TL)                                                \
  do {                                                                         \
    LOADB(L, ((lt) + 1) & 15);                                                 \
    ISSUEA_J(JJ, TL);                                                          \
    SB;                                                                        \
    RD_A(lt);                                                                  \
    MFMA16(U);                                                                 \
    asm volatile("s_waitcnt vmcnt(8)" ::: "memory");                           \
    SB; BAR; SB;                                                               \
  } while (0)

// tail tile (last job): optional B prefetch, no A issue, explicit vmcnt
#define TILET(lt, U, L, DOB, VMW, DOVM)                                        \
  do {                                                                         \
    if (DOB) LOADB(L, (lt) + 1);                                               \
    SB;                                                                        \
    RD_A(lt);                                                                  \
    MFMA16(U);                                                                 \
    if (DOVM) { asm volatile("s_waitcnt " VMW ::: "memory"); }                 \
    SB; BAR; SB;                                                               \
  } while (0)

// direct full-line epilogue for job jj (no LDS, no barriers; stores drain async)
#define EPIL(jj)                                                               \
  do {                                                                         \
    const int m0j_ = m0 + (jj) * 2048;                                         \
    const int cl_ = lane & 31;                                                 \
    const int hi4_ = (lane >> 5) << 2;                                         \
    _Pragma("unroll") for (int g = 0; g < 2; g++) {                            \
      const int col = n0 + (wc * 2 + g) * 32 + cl_;                            \
      const float bs = bscale[col];                                            \
      const float bi = bint[col];                                              \
      _Pragma("unroll") for (int m = 0; m < 4; m++) {                          \
        const int rowb = m0j_ + (wr * 4 + m) * 32 + hi4_;                      \
        _Pragma("unroll") for (int r = 0; r < 16; r++) {                       \
          const int row = rowb + (r & 3) + ((r >> 2) << 3);                    \
          out[(size_t)row * N + col] = ((float)acc[m][g][r] + bi) * bs;        \
        }                                                                      \
      }                                                                        \
    }                                                                          \
  } while (0)

#define ZEROACC                                                                \
  do {                                                                         \
    _Pragma("unroll") for (int i = 0; i < 4; i++)                              \
      _Pragma("unroll") for (int j2 = 0; j2 < 2; j2++)                         \
        _Pragma("unroll") for (int r = 0; r < 16; r++) acc[i][j2][r] = 0;      \
  } while (0)

  // prologue: A(job0: 0..2) staged, B(0) -> bA; vmcnt(8) lands A(0)
  ISSUEA_J(0, 0); ISSUEA_J(0, 1); ISSUEA_J(0, 2);
  LOADB(bA, 0);
  asm volatile("s_waitcnt vmcnt(8)" ::: "memory");
  SB; BAR; SB;

  // jobs 0,1: full-rate 16 tiles, cross-job prefetch at lt=13..15, epilogue overlapped
#pragma unroll 1
  for (int j = 0; j < 2; ++j) {
    TILEF(0,  bA, bB, j, 3);
    TILEF(1,  bB, bA, j, 4);
    TILEF(2,  bA, bB, j, 5);
    TILEF(3,  bB, bA, j, 6);
    TILEF(4,  bA, bB, j, 7);
    TILEF(5,  bB, bA, j, 8);
    TILEF(6,  bA, bB, j, 9);
    TILEF(7,  bB, bA, j, 10);
    TILEF(8,  bA, bB, j, 11);
    TILEF(9,  bB, bA, j, 12);
    TILEF(10, bA, bB, j, 13);
    TILEF(11, bB, bA, j, 14);
    TILEF(12, bA, bB, j, 15);
    TILEF(13, bB, bA, j + 1, 0);
    TILEF(14, bA, bB, j + 1, 1);
    TILEF(15, bB, bA, j + 1, 2);
    EPIL(j);                      // stores drain under next job's K-loop
    ZEROACC;
  }

  // job 2: full tiles 0..12, proper tail 13..15
  TILEF(0,  bA, bB, 2, 3);
  TILEF(1,  bB, bA, 2, 4);
  TILEF(2,  bA, bB, 2, 5);
  TILEF(3,  bB, bA, 2, 6);
  TILEF(4,  bA, bB, 2, 7);
  TILEF(5,  bB, bA, 2, 8);
  TILEF(6,  bA, bB, 2, 9);
  TILEF(7,  bB, bA, 2, 10);
  TILEF(8,  bA, bB, 2, 11);
  TILEF(9,  bB, bA, 2, 12);
  TILEF(10, bA, bB, 2, 13);
  TILEF(11, bB, bA, 2, 14);
  TILEF(12, bA, bB, 2, 15);
  TILET(13, bB, bA, 1, "vmcnt(6)", 1);
  TILET(14, bA, bB, 1, "vmcnt(4)", 1);
  TILET(15, bB, bA, 0, "", 0);
  EPIL(2);

#undef ZEROACC
#undef EPIL
#undef TILET
#undef TILEF
#undef MFMA16
#undef RD_A
#undef ISSUEA_J
#undef LOADB
}

// ---------------- launch ----------------
extern "C" void kernel_launch(void* const* d_in, const int* in_sizes, int n_in,
                              void* d_out, int out_size, void* d_ws, size_t ws_size,
                              hipStream_t stream) {
  const float* hs = (const float*)d_in[0];
  const float* w = (const float*)d_in[1];
  const float* bias = (const float*)d_in[2];
  float* out = (float*)d_out;

  const long long n = (long long)in_sizes[0];     // 50331648
  const int K = K_DIM;                            // 1024
  const int O = in_sizes[2];                      // 1024
  const int M = (int)(n / K);                     // 49152

  // workspace layout
  char* ws = (char*)d_ws;
  unsigned int* amax_u = (unsigned int*)ws;                        // 4 B
  float* parts = (float*)(ws + 1024);                              // 8 KB
  float* bscale = (float*)(ws + 16384);                            // 4 KB
  float* bint = (float*)(ws + 20480);                              // 4 KB
  signed char* wq = (signed char*)(ws + 65536);                    // 1 MB (32-frag)
  signed char* xq = (signed char*)(ws + 65536 + 1048576);          // 48 MB (32-frag)

  hipFuncSetAttribute((const void*)gemm_kernel,
                      hipFuncAttributeMaxDynamicSharedMemorySize, 65536);

  const long long n4 = n / 4;
  absmax_part<<<2048, 256, 0, stream>>>(hs, parts, n4);
  absmax_fin<<<1, 256, 0, stream>>>(parts, amax_u, 2048);
  wquant_kernel<<<O, 256, 0, stream>>>(w, bias, amax_u, wq, bscale, bint);
  aquant_kernel<<<M / 16, 256, 0, stream>>>(hs, amax_u, (uint4*)xq);   // 3072 blocks

  gemm_kernel<<<256, 512, 65536, stream>>>(xq, wq, bscale, bint, out, M, O, K);
}

// Round 14
// 190.410 us; speedup vs baseline: 1.2738x; 1.2738x over previous
//
#include <hip/hip_runtime.h>
#include <stdint.h>

typedef int i32x4 __attribute__((ext_vector_type(4)));

#define K_DIM 1024
#define BM 256
#define BN 256
#define NKT 16   // K-tiles of 64

// Fragment-ordered int8 operand layout (producers aquant/wquant <-> consumer GEMM):
// fragment (F = row/16, T = k/64) is 1KB at offset ((F*16)+T)*1024; byte b
// (l=b>>4, j=b&15) holds value[row=F*16+(l&15)][k=T*64+(l>>4)*16+j].
// -> A gld_lds reads are 1KB contiguous; B fragments load straight to registers.

// ---------------- helpers ----------------
__device__ __forceinline__ int quant1(float v, float inv) {
  float t = rintf(v * inv);                 // round half-to-even, matches jnp.round
  t = fminf(fmaxf(t, -128.0f), 127.0f);     // clip(-n-1, n)
  return (int)t;
}

__device__ __forceinline__ void gld_lds16(const signed char* g, signed char* l) {
  typedef const __attribute__((address_space(1))) unsigned int* gp_t;
  typedef __attribute__((address_space(3))) unsigned int* lp_t;
  __builtin_amdgcn_global_load_lds((gp_t)(const void*)g, (lp_t)(void*)l, 16, 0, 0);
}

#define SB __builtin_amdgcn_sched_barrier(0)
#define BAR __builtin_amdgcn_s_barrier()
#define WAIT_LGKM0 asm volatile("s_waitcnt lgkmcnt(0)" ::: "memory")

// block-local reduce of the 2048 absmax partials (max is order-independent ->
// bit-identical to a separate reduce kernel; partials are L2/L3-hot)
__device__ __forceinline__ float reduce_parts(const float* __restrict__ parts,
                                              float* sm /* >=4 floats LDS */) {
  const int t = threadIdx.x;
  float m = 0.0f;
  for (int i = t; i < 2048; i += 256) m = fmaxf(m, parts[i]);
#pragma unroll
  for (int off = 32; off > 0; off >>= 1) m = fmaxf(m, __shfl_down(m, off, 64));
  const int lane = t & 63, wid = t >> 6;
  if (lane == 0) sm[wid] = m;
  __syncthreads();
  return fmaxf(fmaxf(sm[0], sm[1]), fmaxf(sm[2], sm[3]));
}

// ---------------- 1) absmax partials ----------------
__global__ void absmax_part(const float* __restrict__ x, float* __restrict__ parts,
                            long long n4) {
  long long i = (long long)blockIdx.x * blockDim.x + threadIdx.x;
  const long long stride = (long long)gridDim.x * blockDim.x;
  const float4* x4 = (const float4*)x;
  float m = 0.0f;
  for (; i < n4; i += stride) {
    float4 v = x4[i];
    m = fmaxf(m, fmaxf(fmaxf(fabsf(v.x), fabsf(v.y)), fmaxf(fabsf(v.z), fabsf(v.w))));
  }
#pragma unroll
  for (int off = 32; off > 0; off >>= 1) m = fmaxf(m, __shfl_down(m, off, 64));
  __shared__ float sm[4];
  const int lane = threadIdx.x & 63, wid = threadIdx.x >> 6;
  if (lane == 0) sm[wid] = m;
  __syncthreads();
  if (threadIdx.x == 0)
    parts[blockIdx.x] = fmaxf(fmaxf(sm[0], sm[1]), fmaxf(sm[2], sm[3]));
}

// ---------------- 2) weight quant + bias (frag-ordered wq; self-reduced amax) ----------------
__global__ void wquant_kernel(const float* __restrict__ w, const float* __restrict__ bias,
                              const float* __restrict__ parts,
                              signed char* __restrict__ wq,
                              float* __restrict__ bscale, float* __restrict__ bint) {
  __shared__ float smr[4];
  const float amax = reduce_parts(parts, smr);
  const int o = blockIdx.x;
  const int t = threadIdx.x;          // k = 4t .. 4t+3
  float4 v = ((const float4*)(w + (size_t)o * K_DIM))[t];
  float m = fmaxf(fmaxf(fabsf(v.x), fabsf(v.y)), fmaxf(fabsf(v.z), fabsf(v.w)));
#pragma unroll
  for (int off = 32; off > 0; off >>= 1) m = fmaxf(m, __shfl_down(m, off, 64));
  __shared__ float sm[4];
  __shared__ float s_scale;
  const int lane = t & 63, wid = t >> 6;
  if (lane == 0) sm[wid] = m;
  __syncthreads();
  if (t == 0) {
    float wm = fmaxf(fmaxf(sm[0], sm[1]), fmaxf(sm[2], sm[3]));
    float wsc = fmaxf(wm, 1e-8f) / 127.0f;
    float asc = fmaxf(amax, 1e-8f) / 127.0f;
    float bsc = wsc * asc;
    bscale[o] = bsc;
    bint[o] = rintf(bias[o] / bsc);
    s_scale = wsc;
  }
  __syncthreads();
  const float inv = 1.0f / s_scale;
  int q0 = quant1(v.x, inv), q1 = quant1(v.y, inv), q2 = quant1(v.z, inv), q3 = quant1(v.w, inv);
  unsigned int p = (unsigned)(q0 & 255) | ((unsigned)(q1 & 255) << 8) |
                   ((unsigned)(q2 & 255) << 16) | ((unsigned)(q3 & 255) << 24);
  const int F = o >> 4, T = t >> 4;
  const int l = (((t >> 2) & 3) << 4) | (o & 15);
  const int j = (t << 2) & 15;
  *(unsigned int*)(wq + (((size_t)F << 14) + (T << 10) + (l << 4) + j)) = p;
}

// ---------------- 3) activation quant: coalesced -> LDS frag image -> linear writes ----------------
__global__ __launch_bounds__(256) void aquant_kernel(
    const float* __restrict__ x, const float* __restrict__ parts,
    uint4* __restrict__ q16) {
  __shared__ float smr[4];
  __shared__ unsigned int limg[4096];   // 16KB int8 frag image for this F
  const float amax = reduce_parts(parts, smr);
  const float asc = fmaxf(amax, 1e-8f) / 127.0f;
  const float inv = 1.0f / asc;
  const int F = blockIdx.x;
  const int t = threadIdx.x;
  const int r = t >> 4, kq = t & 15;
  const float* rowp = x + (((size_t)F * 16 + r) << 10);
#pragma unroll
  for (int rep = 0; rep < 16; ++rep) {
    const int fi = rep * 16 + kq;           // float4 index in row, 0..255
    float4 v = ((const float4*)rowp)[fi];
    int q0 = quant1(v.x, inv), q1 = quant1(v.y, inv), q2 = quant1(v.z, inv), q3 = quant1(v.w, inv);
    unsigned int p = (unsigned)(q0 & 255) | ((unsigned)(q1 & 255) << 8) |
                     ((unsigned)(q2 & 255) << 16) | ((unsigned)(q3 & 255) << 24);
    const int k0 = fi << 2;
    const int T = k0 >> 6;
    const int l = (((k0 >> 4) & 3) << 4) | r;
    const int j = k0 & 15;
    limg[(T << 8) + (l << 2) + (j >> 2)] = p;
  }
  __syncthreads();
  const uint4* src = (const uint4*)limg;
#pragma unroll
  for (int rep2 = 0; rep2 < 4; ++rep2)
    q16[((size_t)F << 10) + rep2 * 256 + t] = src[rep2 * 256 + t];
}

// ---------------- 4) int8 GEMM (R9 champion): A via LDS, B->regs, 1 barrier/tile ----------------
__global__ __launch_bounds__(512, 2) void gemm_kernel(
    const signed char* __restrict__ A, const signed char* __restrict__ W,
    const float* __restrict__ bscale, const float* __restrict__ bint,
    float* __restrict__ out, int M, int N, int K) {
  extern __shared__ __align__(16) signed char smem[];   // 65536 B: 4 x [16][1024] A bufs
  signed char* Abase = smem;

  // bijective XCD swizzle (gridDim.x % 8 == 0)
  const int nwg = gridDim.x;
  const int orig = blockIdx.x;
  const int wgid = (orig & 7) * (nwg >> 3) + (orig >> 3);
  const int nbn = N / BN;
  const int bm = wgid / nbn;
  const int bn = wgid % nbn;
  const int m0 = bm * BM, n0 = bn * BN;

  const int tid = threadIdx.x;
  const int lane = tid & 63;
  const int wid = tid >> 6;          // 8 waves
  const int wr = wid >> 2;           // 2 wave-rows
  const int wc = wid & 3;            // 4 wave-cols

  const signed char* gaf = A + (((size_t)(m0 >> 4) + wid) << 14) + (lane << 4);
  const size_t fs8 = (size_t)8 << 14;
  const signed char* gbf = W + (((size_t)(n0 >> 4) + wc * 4) << 14) + (lane << 4);

  i32x4 acc[8][4];
#pragma unroll
  for (int i = 0; i < 8; i++)
#pragma unroll
    for (int j = 0; j < 4; j++) acc[i][j] = (i32x4){0, 0, 0, 0};

  i32x4 af[8];
  i32x4 bfA[4], bfB[4];

#define LOADB(L, tt)                                                           \
  do {                                                                         \
    L[0] = *(const i32x4*)(gbf + ((size_t)0 << 14) + ((tt) << 10));            \
    L[1] = *(const i32x4*)(gbf + ((size_t)1 << 14) + ((tt) << 10));            \
    L[2] = *(const i32x4*)(gbf + ((size_t)2 << 14) + ((tt) << 10));            \
    L[3] = *(const i32x4*)(gbf + ((size_t)3 << 14) + ((tt) << 10));            \
  } while (0)

#define ISSUEA(tt)                                                             \
  do {                                                                         \
    gld_lds16(gaf + ((size_t)(tt) << 10),                                      \
              Abase + ((((tt) & 3) * 16 + wid) << 10));                        \
    gld_lds16(gaf + fs8 + ((size_t)(tt) << 10),                                \
              Abase + ((((tt) & 3) * 16 + wid + 8) << 10));                    \
  } while (0)

#define RD_A(t, i_)                                                            \
  af[i_] = *(const i32x4*)(Abase + ((((t) & 3) * 16 + wr * 8 + (i_)) << 10) + (lane << 4))

#define MFMA16U(IB, U)                                                         \
  do {                                                                         \
    __builtin_amdgcn_s_setprio(1);                                             \
    _Pragma("unroll") for (int i_ = 0; i_ < 4; i_++)                           \
      _Pragma("unroll") for (int j_ = 0; j_ < 4; j_++)                         \
        acc[(IB) + i_][j_] = __builtin_amdgcn_mfma_i32_16x16x64_i8(            \
            af[(IB) + i_], U[j_], acc[(IB) + i_][j_], 0, 0, 0);                \
    __builtin_amdgcn_s_setprio(0);                                             \
  } while (0)

#define TILE(t, U, L, DOB, DOA, VMW, DOVM)                                     \
  do {                                                                         \
    if (DOB) LOADB(L, (t) + 1);                                                \
    if (DOA) ISSUEA((t) + 3);                                                  \
    SB;                                                                        \
    RD_A(t, 0); RD_A(t, 1); RD_A(t, 2); RD_A(t, 3);                            \
    RD_A(t, 4); RD_A(t, 5); RD_A(t, 6); RD_A(t, 7);                            \
    MFMA16U(0, U);                                                             \
    MFMA16U(4, U);                                                             \
    if (DOVM) { asm volatile("s_waitcnt " VMW ::: "memory"); }                 \
    SB; BAR; SB;                                                               \
  } while (0)

  ISSUEA(0); ISSUEA(1); ISSUEA(2);
  LOADB(bfA, 0);
  asm volatile("s_waitcnt vmcnt(0)" ::: "memory");
  SB; BAR; SB;

  TILE(0,  bfA, bfB, 1, 1, "vmcnt(8)", 1);
  TILE(1,  bfB, bfA, 1, 1, "vmcnt(8)", 1);
  TILE(2,  bfA, bfB, 1, 1, "vmcnt(8)", 1);
  TILE(3,  bfB, bfA, 1, 1, "vmcnt(8)", 1);
  TILE(4,  bfA, bfB, 1, 1, "vmcnt(8)", 1);
  TILE(5,  bfB, bfA, 1, 1, "vmcnt(8)", 1);
  TILE(6,  bfA, bfB, 1, 1, "vmcnt(8)", 1);
  TILE(7,  bfB, bfA, 1, 1, "vmcnt(8)", 1);
  TILE(8,  bfA, bfB, 1, 1, "vmcnt(8)", 1);
  TILE(9,  bfB, bfA, 1, 1, "vmcnt(8)", 1);
  TILE(10, bfA, bfB, 1, 1, "vmcnt(8)", 1);
  TILE(11, bfB, bfA, 1, 1, "vmcnt(8)", 1);
  TILE(12, bfA, bfB, 1, 1, "vmcnt(8)", 1);
  TILE(13, bfB, bfA, 1, 0, "vmcnt(6)", 1);   // last A (A15) issued at t=12
  TILE(14, bfA, bfB, 1, 0, "vmcnt(4)", 1);   // forces A15 landed (FIFO)
  TILE(15, bfB, bfA, 0, 0, "", 0);

#undef TILE
#undef MFMA16U
#undef RD_A
#undef ISSUEA
#undef LOADB

  // ---- epilogue: LDS-staged coalesced C writes (exact-ideal 196.6MB), 4x 64-row quarters ----
  float* Cst = (float*)smem;
  const int rr = (lane >> 4) * 4;
  const int cc = lane & 15;
#pragma unroll
  for (int q = 0; q < 4; ++q) {
    if (wr == (q >> 1)) {
#pragma unroll
      for (int j = 0; j < 4; j++) {
        const int colL = wc * 64 + j * 16 + cc;
        const float bs = bscale[n0 + colL];
        const float bi = bint[n0 + colL];
#pragma unroll
        for (int i2 = 0; i2 < 4; i2++) {
          const int i = (q & 1) * 4 + i2;
#pragma unroll
          for (int r = 0; r < 4; r++)
            Cst[(i2 * 16 + rr + r) * 256 + colL] = ((float)acc[i][j][r] + bi) * bs;
        }
      }
    }
    WAIT_LGKM0;
    BAR;
    const size_t rowbase = (size_t)(m0 + q * 64) * N + n0;
#pragma unroll
    for (int it = 0; it < 8; ++it) {
      const int r_ = it * 8 + wid;                  // 0..63
      float4 v = *(const float4*)&Cst[r_ * 256 + lane * 4];
      *(float4*)&out[rowbase + (size_t)r_ * N + lane * 4] = v;
    }
    WAIT_LGKM0;
    BAR;
  }
}

// ---------------- launch ----------------
extern "C" void kernel_launch(void* const* d_in, const int* in_sizes, int n_in,
                              void* d_out, int out_size, void* d_ws, size_t ws_size,
                              hipStream_t stream) {
  const float* hs = (const float*)d_in[0];
  const float* w = (const float*)d_in[1];
  const float* bias = (const float*)d_in[2];
  float* out = (float*)d_out;

  const long long n = (long long)in_sizes[0];     // 50331648
  const int K = K_DIM;                            // 1024
  const int O = in_sizes[2];                      // 1024
  const int M = (int)(n / K);                     // 49152

  // workspace layout
  char* ws = (char*)d_ws;
  float* parts = (float*)(ws + 1024);                              // 8 KB
  float* bscale = (float*)(ws + 16384);                            // 4 KB
  float* bint = (float*)(ws + 20480);                              // 4 KB
  signed char* wq = (signed char*)(ws + 65536);                    // 1 MB (frag-ordered)
  signed char* xq = (signed char*)(ws + 65536 + 1048576);          // 48 MB (frag-ordered)

  hipFuncSetAttribute((const void*)gemm_kernel,
                      hipFuncAttributeMaxDynamicSharedMemorySize, 65536);

  const long long n4 = n / 4;
  absmax_part<<<2048, 256, 0, stream>>>(hs, parts, n4);
  wquant_kernel<<<O, 256, 0, stream>>>(w, bias, parts, wq, bscale, bint);
  aquant_kernel<<<M / 16, 256, 0, stream>>>(hs, parts, (uint4*)xq);   // 3072 blocks

  const int nblocks = (M / BM) * (O / BN);        // 192 * 4 = 768
  gemm_kernel<<<nblocks, 512, 65536, stream>>>(xq, wq, bscale, bint, out, M, O, K);
}